// Round 1
// baseline (5116.708 us; speedup 1.0000x reference)
//
#include <hip/hip_runtime.h>
#include <cstddef>

#define DIM   1024
#define VOCAB 32000
#define BATCH 2
#define SEQ   2048
#define CTX   4
#define EPS_D 1e-6f
#define LN_EPS 1e-5f

// ---------------------------------------------------------------------------
// K1: embedding gather + local context sum (sum of rows at s, s-1, s-2, s-3)
// grid = B*S blocks, 256 threads, each thread handles 4 consecutive dims
// ---------------------------------------------------------------------------
__global__ __launch_bounds__(256)
void embed_ctx_kernel(const int* __restrict__ x,
                      const float* __restrict__ table,
                      float* __restrict__ emb) {
    int bs = blockIdx.x;                 // 0..B*S-1
    int b = bs >> 11;                    // /SEQ
    int s = bs & (SEQ - 1);
    int d = threadIdx.x * 4;
    float4 acc = make_float4(0.f, 0.f, 0.f, 0.f);
    #pragma unroll
    for (int o = 0; o < CTX; ++o) {
        int ss = s - o;
        if (ss >= 0) {
            int row = x[b * SEQ + ss];
            const float4 v = *(const float4*)&table[(size_t)row * DIM + d];
            acc.x += v.x; acc.y += v.y; acc.z += v.z; acc.w += v.w;
        }
    }
    *(float4*)&emb[(size_t)bs * DIM + d] = acc;
}

// ---------------------------------------------------------------------------
// Generic fp32 GEMM: C[M,N] = act( (A[M,K] @ B[K,N]) / rowdiv[m] + bias[n] )
// 64x64 tile, BK=16, 256 threads, 4x4 microtile per thread.
// All shapes in this problem are multiples of 64/16 -> no bounds checks.
// ACT: 0 = none, 1 = elu(x)+1
// ---------------------------------------------------------------------------
template<int ACT, bool HAS_BIAS, bool HAS_DIV>
__global__ __launch_bounds__(256)
void gemm_kernel(const float* __restrict__ A,
                 const float* __restrict__ B,
                 const float* __restrict__ bias,
                 const float* __restrict__ rowdiv,
                 float* __restrict__ C,
                 int M, int N, int K) {
    __shared__ float As[16][64];   // As[k][m]
    __shared__ float Bs[16][64];   // Bs[k][n]

    const int tid = threadIdx.x;
    const int tx = tid & 15;       // 0..15 -> col group
    const int ty = tid >> 4;       // 0..15 -> row group
    const int row0 = blockIdx.y * 64;
    const int col0 = blockIdx.x * 64;

    // loaders
    const int a_row = tid >> 2;            // 0..63
    const int a_col = (tid & 3) * 4;       // 0,4,8,12
    const int b_row = tid >> 4;            // 0..15
    const int b_col = (tid & 15) * 4;      // 0..60

    const float* Aptr = A + (size_t)(row0 + a_row) * K + a_col;
    const float* Bptr = B + (size_t)b_row * N + col0 + b_col;

    float acc[4][4];
    #pragma unroll
    for (int i = 0; i < 4; ++i)
        #pragma unroll
        for (int j = 0; j < 4; ++j) acc[i][j] = 0.f;

    for (int k0 = 0; k0 < K; k0 += 16) {
        float4 a4 = *(const float4*)(Aptr + k0);
        float4 b4 = *(const float4*)(Bptr + (size_t)k0 * N);
        As[a_col + 0][a_row] = a4.x;
        As[a_col + 1][a_row] = a4.y;
        As[a_col + 2][a_row] = a4.z;
        As[a_col + 3][a_row] = a4.w;
        *(float4*)&Bs[b_row][b_col] = b4;
        __syncthreads();
        #pragma unroll
        for (int kk = 0; kk < 16; ++kk) {
            float4 av = *(const float4*)&As[kk][ty * 4];
            float4 bv = *(const float4*)&Bs[kk][tx * 4];
            float am[4] = {av.x, av.y, av.z, av.w};
            float bm[4] = {bv.x, bv.y, bv.z, bv.w};
            #pragma unroll
            for (int i = 0; i < 4; ++i)
                #pragma unroll
                for (int j = 0; j < 4; ++j)
                    acc[i][j] = fmaf(am[i], bm[j], acc[i][j]);
        }
        __syncthreads();
    }

    #pragma unroll
    for (int i = 0; i < 4; ++i) {
        const int r = row0 + ty * 4 + i;
        float rdiv = 1.f;
        if (HAS_DIV) rdiv = 1.f / rowdiv[r];
        #pragma unroll
        for (int j = 0; j < 4; ++j) {
            const int c = col0 + tx * 4 + j;
            float v = acc[i][j] * rdiv;
            if (HAS_BIAS) v += bias[c];
            if (ACT == 1) v = (v > 0.f) ? (v + 1.f) : __expf(v);
            C[(size_t)r * N + c] = v;
        }
    }
}

// ---------------------------------------------------------------------------
// Causal scores: scores[b,i,j] = (j<=i) ? dot(q[b,i,:], k[b,j,:]) : 0
// Same tiling; blocks entirely above the diagonal just write zeros.
// grid = (S/64, S/64, B)
// ---------------------------------------------------------------------------
__global__ __launch_bounds__(256)
void scores_kernel(const float* __restrict__ q,
                   const float* __restrict__ k,
                   float* __restrict__ scores) {
    const int b = blockIdx.z;
    const int tid = threadIdx.x;
    const int tx = tid & 15;
    const int ty = tid >> 4;
    const int i0 = blockIdx.y * 64;
    const int j0 = blockIdx.x * 64;
    float* Sc = scores + (size_t)b * SEQ * SEQ;

    if (j0 > i0 + 63) {   // fully masked -> write zeros (ws is poisoned)
        #pragma unroll
        for (int i = 0; i < 4; ++i)
            #pragma unroll
            for (int j = 0; j < 4; ++j)
                Sc[(size_t)(i0 + ty * 4 + i) * SEQ + j0 + tx * 4 + j] = 0.f;
        return;
    }

    const float* Q = q + (size_t)b * SEQ * DIM;
    const float* Kp = k + (size_t)b * SEQ * DIM;

    __shared__ float Qs[16][64];   // Qs[d][i]
    __shared__ float Ks[16][64];   // Ks[d][j]

    const int l_row = tid >> 2;        // 0..63
    const int l_col = (tid & 3) * 4;

    const float* Qptr = Q + (size_t)(i0 + l_row) * DIM + l_col;
    const float* Kptr = Kp + (size_t)(j0 + l_row) * DIM + l_col;

    float acc[4][4];
    #pragma unroll
    for (int i = 0; i < 4; ++i)
        #pragma unroll
        for (int j = 0; j < 4; ++j) acc[i][j] = 0.f;

    for (int d0 = 0; d0 < DIM; d0 += 16) {
        float4 a4 = *(const float4*)(Qptr + d0);
        float4 b4 = *(const float4*)(Kptr + d0);
        Qs[l_col + 0][l_row] = a4.x;
        Qs[l_col + 1][l_row] = a4.y;
        Qs[l_col + 2][l_row] = a4.z;
        Qs[l_col + 3][l_row] = a4.w;
        Ks[l_col + 0][l_row] = b4.x;
        Ks[l_col + 1][l_row] = b4.y;
        Ks[l_col + 2][l_row] = b4.z;
        Ks[l_col + 3][l_row] = b4.w;
        __syncthreads();
        #pragma unroll
        for (int kk = 0; kk < 16; ++kk) {
            float4 av = *(const float4*)&Qs[kk][ty * 4];
            float4 bv = *(const float4*)&Ks[kk][tx * 4];
            float am[4] = {av.x, av.y, av.z, av.w};
            float bm[4] = {bv.x, bv.y, bv.z, bv.w};
            #pragma unroll
            for (int i = 0; i < 4; ++i)
                #pragma unroll
                for (int j = 0; j < 4; ++j)
                    acc[i][j] = fmaf(am[i], bm[j], acc[i][j]);
        }
        __syncthreads();
    }

    #pragma unroll
    for (int i = 0; i < 4; ++i) {
        const int ii = i0 + ty * 4 + i;
        #pragma unroll
        for (int j = 0; j < 4; ++j) {
            const int jj = j0 + tx * 4 + j;
            Sc[(size_t)ii * SEQ + jj] = (jj <= ii) ? acc[i][j] : 0.f;
        }
    }
}

// ---------------------------------------------------------------------------
// Block reduce helper (256 threads = 4 waves)
// ---------------------------------------------------------------------------
__device__ __forceinline__ float block_reduce_sum(float v, float* red) {
    #pragma unroll
    for (int off = 32; off > 0; off >>= 1) v += __shfl_down(v, off);
    const int lane = threadIdx.x & 63;
    const int wid = threadIdx.x >> 6;
    if (lane == 0) red[wid] = v;
    __syncthreads();
    float s = red[0] + red[1] + red[2] + red[3];
    return s;
}

// ---------------------------------------------------------------------------
// den[b,i] = sum_j scores[b,i,j] + EPS  (zeros above diagonal already written)
// grid = B*S blocks
// ---------------------------------------------------------------------------
__global__ __launch_bounds__(256)
void den_kernel(const float* __restrict__ scores, float* __restrict__ den) {
    const int row = blockIdx.x;          // 0..B*S-1
    const int b = row >> 11;
    const int i = row & (SEQ - 1);
    const float* r = scores + (size_t)b * SEQ * SEQ + (size_t)i * SEQ;
    float s = 0.f;
    for (int j = threadIdx.x * 4; j < SEQ; j += 256 * 4) {
        float4 v = *(const float4*)&r[j];
        s += v.x + v.y + v.z + v.w;
    }
    __shared__ float red[4];
    float tot = block_reduce_sum(s, red);
    if (threadIdx.x == 0) den[row] = tot + EPS_D;
}

// ---------------------------------------------------------------------------
// LayerNorm in-place over rows of DIM. grid = B*S blocks, 256 threads x 4 elems
// ---------------------------------------------------------------------------
__global__ __launch_bounds__(256)
void ln_kernel(float* __restrict__ io,
               const float* __restrict__ gamma,
               const float* __restrict__ beta) {
    const size_t row = blockIdx.x;
    float* r = io + row * DIM;
    const int d = threadIdx.x * 4;
    float4 v = *(const float4*)&r[d];
    float s = v.x + v.y + v.z + v.w;
    float sq = v.x * v.x + v.y * v.y + v.z * v.z + v.w * v.w;
    __shared__ float r1[4];
    __shared__ float r2[4];
    float tot = block_reduce_sum(s, r1);
    __syncthreads();
    float totsq = block_reduce_sum(sq, r2);
    const float mu = tot * (1.f / DIM);
    const float var = totsq * (1.f / DIM) - mu * mu;
    const float rs = rsqrtf(var + LN_EPS);
    float4 gv = *(const float4*)&gamma[d];
    float4 bv = *(const float4*)&beta[d];
    v.x = (v.x - mu) * rs * gv.x + bv.x;
    v.y = (v.y - mu) * rs * gv.y + bv.y;
    v.z = (v.z - mu) * rs * gv.z + bv.z;
    v.w = (v.w - mu) * rs * gv.w + bv.w;
    *(float4*)&r[d] = v;
}

// ---------------------------------------------------------------------------
// Host launch
// ---------------------------------------------------------------------------
extern "C" void kernel_launch(void* const* d_in, const int* in_sizes, int n_in,
                              void* d_out, int out_size, void* d_ws, size_t ws_size,
                              hipStream_t stream) {
    const int*   x     = (const int*)d_in[0];
    const float* table = (const float*)d_in[1];
    const float* Wq    = (const float*)d_in[2];
    const float* bq    = (const float*)d_in[3];
    const float* Wk    = (const float*)d_in[4];
    const float* bk    = (const float*)d_in[5];
    const float* Wv    = (const float*)d_in[6];
    const float* bv    = (const float*)d_in[7];
    const float* Wo    = (const float*)d_in[8];
    const float* bo    = (const float*)d_in[9];
    const float* gamma = (const float*)d_in[10];
    const float* beta  = (const float*)d_in[11];
    const float* Wout  = (const float*)d_in[12];
    const float* bout  = (const float*)d_in[13];
    float* logits = (float*)d_out;

    const int M = BATCH * SEQ;                 // 4096
    const size_t NE = (size_t)M * DIM;         // 4 Mi floats

    float* ws    = (float*)d_ws;
    float* emb   = ws;                         // [M, D]
    float* q     = ws + NE;                    // [M, D]
    float* k     = ws + 2 * NE;                // [M, D]
    float* v     = ws + 3 * NE;                // [M, D]
    float* sc    = ws + 4 * NE;                // [B, S, S]  (8 Mi floats)
    float* den   = ws + 4 * NE + (size_t)BATCH * SEQ * SEQ;  // [B*S]
    float* attn  = emb;                        // reuse emb after qkv
    float* out   = q;                          // reuse q after scores

    // 1. embedding + local context
    embed_ctx_kernel<<<M, 256, 0, stream>>>(x, table, emb);

    // 2. q,k,v projections
    dim3 gq(DIM / 64, M / 64);
    gemm_kernel<1, true, false><<<gq, 256, 0, stream>>>(emb, Wq, bq, nullptr, q, M, DIM, DIM);
    gemm_kernel<1, true, false><<<gq, 256, 0, stream>>>(emb, Wk, bk, nullptr, k, M, DIM, DIM);
    gemm_kernel<0, true, false><<<gq, 256, 0, stream>>>(emb, Wv, bv, nullptr, v, M, DIM, DIM);

    // 3. causal scores + denominator
    dim3 gs(SEQ / 64, SEQ / 64, BATCH);
    scores_kernel<<<gs, 256, 0, stream>>>(q, k, sc);
    den_kernel<<<M, 256, 0, stream>>>(sc, den);

    // 4. num = scores @ v, scaled by 1/den (per batch)
    dim3 gn(DIM / 64, SEQ / 64);
    for (int b = 0; b < BATCH; ++b) {
        gemm_kernel<0, false, true><<<gn, 256, 0, stream>>>(
            sc + (size_t)b * SEQ * SEQ, v + (size_t)b * SEQ * DIM,
            nullptr, den + (size_t)b * SEQ,
            attn + (size_t)b * SEQ * DIM, SEQ, DIM, SEQ);
    }

    // 5. out = attn @ Wo + bo
    gemm_kernel<0, true, false><<<gq, 256, 0, stream>>>(attn, Wo, bo, nullptr, out, M, DIM, DIM);

    // 6. LayerNorm in-place
    ln_kernel<<<M, 256, 0, stream>>>(out, gamma, beta);

    // 7. logits = out @ Wout + bout
    dim3 gl(VOCAB / 64, M / 64);
    gemm_kernel<0, true, false><<<gl, 256, 0, stream>>>(out, Wout, bout, nullptr, logits, M, VOCAB, DIM);
}